// Round 1
// baseline (509.049 us; speedup 1.0000x reference)
//
#include <hip/hip_runtime.h>

#define T_TOKENS 2048
#define HIDDEN   2048
#define NEXPERT  32
#define TOPK     4
#define INTER    768
#define NPAIRS   (T_TOKENS*TOPK)   /* 8192 */
#define BM       128
#define BK       32
#define MT_MAX   95                /* sum ceil(cnt/128) <= 8192/128 + 31 = 95 */
#define NT1      12                /* 768/64 gated col-tiles */
#define NT2      16                /* 2048/128 out col-tiles */

typedef short  bh8 __attribute__((ext_vector_type(8)));   // 8 bf16 (4 VGPRs)
typedef float  fx4 __attribute__((ext_vector_type(4)));
typedef unsigned short us4 __attribute__((ext_vector_type(4)));

__device__ __forceinline__ unsigned short f2bf(float f){
    unsigned int u = __float_as_uint(f);
    u += 0x7FFFu + ((u >> 16) & 1u);            // RNE
    return (unsigned short)(u >> 16);
}
__device__ __forceinline__ bh8 pk8(float4 a, float4 b){
    bh8 r;
    r[0]=(short)f2bf(a.x); r[1]=(short)f2bf(a.y); r[2]=(short)f2bf(a.z); r[3]=(short)f2bf(a.w);
    r[4]=(short)f2bf(b.x); r[5]=(short)f2bf(b.y); r[6]=(short)f2bf(b.z); r[7]=(short)f2bf(b.w);
    return r;
}

/* ---------------- router: logits, softmax-top4, counts ---------------- */
__global__ void router_k(const float* __restrict__ x, const float* __restrict__ gate,
                         int* __restrict__ topk_id, float* __restrict__ topk_w,
                         int* __restrict__ counts){
    const int t = blockIdx.x;
    const int l = threadIdx.x;
    const float* xr = x + (size_t)t*HIDDEN;
    float acc[NEXPERT];
#pragma unroll
    for (int e=0;e<NEXPERT;e++) acc[e]=0.f;
    for (int d=l; d<HIDDEN; d+=64){
        float xv = xr[d];
        const float4* g4 = (const float4*)(gate + (size_t)d*NEXPERT);
#pragma unroll
        for (int i=0;i<8;i++){
            float4 g = g4[i];
            acc[i*4+0] += xv*g.x; acc[i*4+1] += xv*g.y;
            acc[i*4+2] += xv*g.z; acc[i*4+3] += xv*g.w;
        }
    }
#pragma unroll
    for (int e=0;e<NEXPERT;e++){
#pragma unroll
        for (int m=1;m<64;m<<=1) acc[e] += __shfl_xor(acc[e], m, 64);
    }
    // every lane now holds all 32 logits; compute top-4 redundantly (uniform)
    int ids[TOPK]; float lv[TOPK];
#pragma unroll
    for (int k=0;k<TOPK;k++){
        float m=-1e30f; int mi=0;
#pragma unroll
        for (int e=0;e<NEXPERT;e++){ if (acc[e]>m){ m=acc[e]; mi=e; } }
        ids[k]=mi; lv[k]=m; acc[mi]=-1e30f;
    }
    float ex[TOPK]; float s=0.f;
#pragma unroll
    for (int k=0;k<TOPK;k++){ ex[k]=__expf(lv[k]-lv[0]); s+=ex[k]; }
    if (l==0){
        float inv = 1.f/s;
#pragma unroll
        for (int k=0;k<TOPK;k++){
            topk_id[t*TOPK+k]=ids[k];
            topk_w[t*TOPK+k]=ex[k]*inv;
            atomicAdd(&counts[ids[k]],1);
        }
    }
}

/* ---------------- schedule: prefix sums + tile list ---------------- */
__global__ void sched_k(const int* __restrict__ counts, int* __restrict__ offs,
                        int* __restrict__ cursors, int* __restrict__ nmt,
                        int* __restrict__ te, int* __restrict__ tr0, int* __restrict__ trn){
    if (threadIdx.x==0 && blockIdx.x==0){
        int tot=0, nm=0;
        for (int e=0;e<NEXPERT;e++){
            int c = counts[e];
            offs[e]=tot; cursors[e]=tot;
            for (int s=0;s<c;s+=BM){
                te[nm]=e; tr0[nm]=tot+s; trn[nm]=(c-s)<BM?(c-s):BM; nm++;
            }
            tot+=c;
        }
        *nmt = nm;
    }
}

/* ---------------- scatter pairs into expert buckets ---------------- */
__global__ void scatter_k(const int* __restrict__ topk_id, const float* __restrict__ topk_w,
                          int* __restrict__ cursors, int* __restrict__ pair_tok,
                          float* __restrict__ pair_w){
    int g = blockIdx.x*256 + threadIdx.x;     // 8192 pairs
    int e = topk_id[g];
    float w = topk_w[g];
    int pos = atomicAdd(&cursors[e],1);
    pair_tok[pos] = g>>2;
    pair_w[pos]  = w;
}

/* ---------------- grouped GEMM1: x -> silu(g)*u*w, bf16 ---------------- */
__global__ __launch_bounds__(256) void gemm1_k(
        const float* __restrict__ x, const float* __restrict__ gup,
        const int* __restrict__ nmt, const int* __restrict__ te,
        const int* __restrict__ tr0, const int* __restrict__ trn,
        const int* __restrict__ pair_tok, const float* __restrict__ pair_w,
        unsigned short* __restrict__ gated){
    __shared__ unsigned short As[BM*40];     // [row][k] pitch 40 shorts (80B)
    __shared__ unsigned short Bs[BM*40];     // [col][k] transposed, chunk-XOR swizzled
    __shared__ int   s_tok[BM];
    __shared__ float s_w[BM];

    // m204 bijective XCD-chunked swizzle: consecutive logical ids -> same XCD
    const int nwg = gridDim.x;
    const int q = nwg>>3, r = nwg&7;
    const int xcd = blockIdx.x & 7, idx = blockIdx.x >> 3;
    const int L = (xcd<r ? xcd*(q+1) : r*(q+1)+(xcd-r)*q) + idx;
    const int mt = L % MT_MAX, nt = L / MT_MAX;   // mt innermost: B-panel L2 reuse
    if (mt >= *nmt) return;
    const int e = te[mt], row0 = tr0[mt], rows = trn[mt];
    const int n0 = nt*64;

    const int t = threadIdx.x;
    if (t < BM){
        int p = row0 + t; if (p > NPAIRS-1) p = NPAIRS-1;
        s_tok[t] = pair_tok[p];
        s_w[t]   = pair_w[p];
    }
    __syncthreads();

    const int lane = t & 63, w = t >> 6;
    const int l15 = lane & 15, kb = lane >> 4;
    fx4 acc[2][8];
#pragma unroll
    for (int i=0;i<2;i++)
#pragma unroll
        for (int j=0;j<8;j++) acc[i][j] = (fx4)0.f;

    const float* bbase = gup + (size_t)e*HIDDEN*(2*INTER);
    const int ar = t>>1, akh = (t&1)*16;
    const int atok = s_tok[ar];
    const int bf0 = (t&31)*4, bd0 = (t>>5)*4;
    const int bch = bd0>>3, bhalf = ((bd0>>2)&1)*8;
    const int fc = (bf0 < 64) ? (n0 + bf0) : (768 + n0 + (bf0 - 64));

    for (int kt=0; kt<HIDDEN; kt+=BK){
        __syncthreads();
        {   // stage A: gathered x rows, f32 -> bf16
            const float4* src = (const float4*)(x + (size_t)atok*HIDDEN + kt + akh);
            float4 v0=src[0], v1=src[1], v2=src[2], v3=src[3];
            bh8* dst = (bh8*)&As[ar*40 + akh];
            dst[0]=pk8(v0,v1); dst[1]=pk8(v2,v3);
        }
        {   // stage B: 4x4 micro-tile register transpose, f32 -> bf16
            float4 rv0 = *(const float4*)(bbase + (size_t)(kt+bd0+0)*(2*INTER) + fc);
            float4 rv1 = *(const float4*)(bbase + (size_t)(kt+bd0+1)*(2*INTER) + fc);
            float4 rv2 = *(const float4*)(bbase + (size_t)(kt+bd0+2)*(2*INTER) + fc);
            float4 rv3 = *(const float4*)(bbase + (size_t)(kt+bd0+3)*(2*INTER) + fc);
            us4 c0 = { f2bf(rv0.x), f2bf(rv1.x), f2bf(rv2.x), f2bf(rv3.x) };
            us4 c1 = { f2bf(rv0.y), f2bf(rv1.y), f2bf(rv2.y), f2bf(rv3.y) };
            us4 c2 = { f2bf(rv0.z), f2bf(rv1.z), f2bf(rv2.z), f2bf(rv3.z) };
            us4 c3 = { f2bf(rv0.w), f2bf(rv1.w), f2bf(rv2.w), f2bf(rv3.w) };
            char* bsb = (char*)Bs;
            *(us4*)(bsb + (bf0+0)*80 + ((bch ^ 0)<<4) + bhalf) = c0;
            *(us4*)(bsb + (bf0+1)*80 + ((bch ^ 1)<<4) + bhalf) = c1;
            *(us4*)(bsb + (bf0+2)*80 + ((bch ^ 2)<<4) + bhalf) = c2;
            *(us4*)(bsb + (bf0+3)*80 + ((bch ^ 3)<<4) + bhalf) = c3;
        }
        __syncthreads();
        bh8 a0 = *(const bh8*)&As[(w*32 +      l15)*40 + kb*8];
        bh8 a1 = *(const bh8*)&As[(w*32 + 16 + l15)*40 + kb*8];
        const char* bsb = (const char*)Bs;
#pragma unroll
        for (int c=0;c<8;c++){
            bh8 b = *(const bh8*)(bsb + (c*16+l15)*80 + ((kb ^ (l15&3))<<4));
            acc[0][c] = __builtin_amdgcn_mfma_f32_16x16x32_bf16(a0, b, acc[0][c], 0,0,0);
            acc[1][c] = __builtin_amdgcn_mfma_f32_16x16x32_bf16(a1, b, acc[1][c], 0,0,0);
        }
    }

    // epilogue: gated = silu(g)*u*router_w, bf16
    const int rbase = w*32 + kb*4;
#pragma unroll
    for (int mr=0;mr<2;mr++){
#pragma unroll
        for (int qq=0;qq<4;qq++){
            int row = rbase + mr*16 + qq;
            if (row < rows){
                float wgt = s_w[row];
                size_t prow = (size_t)(row0 + row)*INTER + n0 + l15;
#pragma unroll
                for (int c=0;c<4;c++){
                    float g = acc[mr][c][qq], u = acc[mr][c+4][qq];
                    float sil = g / (1.f + __expf(-g));
                    gated[prow + c*16] = f2bf(sil*u*wgt);
                }
            }
        }
    }
}

/* ---------------- grouped GEMM2: gated -> out (atomic f32) ---------------- */
__global__ __launch_bounds__(256) void gemm2_k(
        const unsigned short* __restrict__ gated, const float* __restrict__ down,
        const int* __restrict__ nmt, const int* __restrict__ te,
        const int* __restrict__ tr0, const int* __restrict__ trn,
        const int* __restrict__ pair_tok, float* __restrict__ out){
    __shared__ unsigned short As[BM*40];
    __shared__ unsigned short Bs[BM*40];
    __shared__ int s_tok[BM];

    const int nwg = gridDim.x;
    const int q = nwg>>3, r = nwg&7;
    const int xcd = blockIdx.x & 7, idx = blockIdx.x >> 3;
    const int L = (xcd<r ? xcd*(q+1) : r*(q+1)+(xcd-r)*q) + idx;
    const int mt = L % MT_MAX, nt = L / MT_MAX;
    if (mt >= *nmt) return;
    const int e = te[mt], row0 = tr0[mt], rows = trn[mt];
    const int n0 = nt*128;

    const int t = threadIdx.x;
    if (t < BM){
        int p = row0 + t; if (p > NPAIRS-1) p = NPAIRS-1;
        s_tok[t] = pair_tok[p];
    }
    __syncthreads();

    const int lane = t & 63, w = t >> 6;
    const int l15 = lane & 15, kb = lane >> 4;
    fx4 acc[2][8];
#pragma unroll
    for (int i=0;i<2;i++)
#pragma unroll
        for (int j=0;j<8;j++) acc[i][j] = (fx4)0.f;

    const float* bbase = down + (size_t)e*INTER*HIDDEN;
    const int ar = t>>1, akh = (t&1)*16;
    int ap = row0 + ar; if (ap > NPAIRS-1) ap = NPAIRS-1;
    const unsigned short* asrc = gated + (size_t)ap*INTER + akh;
    const int bf0 = (t&31)*4, bd0 = (t>>5)*4;
    const int bch = bd0>>3, bhalf = ((bd0>>2)&1)*8;
    const int fc = n0 + bf0;

    for (int kt=0; kt<INTER; kt+=BK){
        __syncthreads();
        {   // stage A: already bf16
            const bh8* s = (const bh8*)(asrc + kt);
            bh8 v0=s[0], v1=s[1];
            bh8* dst = (bh8*)&As[ar*40 + akh];
            dst[0]=v0; dst[1]=v1;
        }
        {   // stage B: transpose down_proj rows
            float4 rv0 = *(const float4*)(bbase + (size_t)(kt+bd0+0)*HIDDEN + fc);
            float4 rv1 = *(const float4*)(bbase + (size_t)(kt+bd0+1)*HIDDEN + fc);
            float4 rv2 = *(const float4*)(bbase + (size_t)(kt+bd0+2)*HIDDEN + fc);
            float4 rv3 = *(const float4*)(bbase + (size_t)(kt+bd0+3)*HIDDEN + fc);
            us4 c0 = { f2bf(rv0.x), f2bf(rv1.x), f2bf(rv2.x), f2bf(rv3.x) };
            us4 c1 = { f2bf(rv0.y), f2bf(rv1.y), f2bf(rv2.y), f2bf(rv3.y) };
            us4 c2 = { f2bf(rv0.z), f2bf(rv1.z), f2bf(rv2.z), f2bf(rv3.z) };
            us4 c3 = { f2bf(rv0.w), f2bf(rv1.w), f2bf(rv2.w), f2bf(rv3.w) };
            char* bsb = (char*)Bs;
            *(us4*)(bsb + (bf0+0)*80 + ((bch ^ 0)<<4) + bhalf) = c0;
            *(us4*)(bsb + (bf0+1)*80 + ((bch ^ 1)<<4) + bhalf) = c1;
            *(us4*)(bsb + (bf0+2)*80 + ((bch ^ 2)<<4) + bhalf) = c2;
            *(us4*)(bsb + (bf0+3)*80 + ((bch ^ 3)<<4) + bhalf) = c3;
        }
        __syncthreads();
        bh8 a0 = *(const bh8*)&As[(w*32 +      l15)*40 + kb*8];
        bh8 a1 = *(const bh8*)&As[(w*32 + 16 + l15)*40 + kb*8];
        const char* bsb = (const char*)Bs;
#pragma unroll
        for (int c=0;c<8;c++){
            bh8 b = *(const bh8*)(bsb + (c*16+l15)*80 + ((kb ^ (l15&3))<<4));
            acc[0][c] = __builtin_amdgcn_mfma_f32_16x16x32_bf16(a0, b, acc[0][c], 0,0,0);
            acc[1][c] = __builtin_amdgcn_mfma_f32_16x16x32_bf16(a1, b, acc[1][c], 0,0,0);
        }
    }

    const int rbase = w*32 + kb*4;
#pragma unroll
    for (int mr=0;mr<2;mr++){
#pragma unroll
        for (int qq=0;qq<4;qq++){
            int row = rbase + mr*16 + qq;
            if (row < rows){
                float* orow = out + (size_t)s_tok[row]*HIDDEN + n0 + l15;
#pragma unroll
                for (int c=0;c<8;c++)
                    atomicAdd(orow + c*16, acc[mr][c][qq]);
            }
        }
    }
}

/* ---------------- host launch ---------------- */
extern "C" void kernel_launch(void* const* d_in, const int* in_sizes, int n_in,
                              void* d_out, int out_size, void* d_ws, size_t ws_size,
                              hipStream_t stream){
    const float* x    = (const float*)d_in[0];
    const float* gate = (const float*)d_in[1];
    const float* gup  = (const float*)d_in[2];
    const float* down = (const float*)d_in[3];
    float* out = (float*)d_out;
    char*  ws  = (char*)d_ws;

    int*   topk_id  = (int*)  (ws + 0x00000);
    float* topk_w   = (float*)(ws + 0x08000);
    int*   counts   = (int*)  (ws + 0x10000);
    int*   cursors  = (int*)  (ws + 0x10080);
    int*   offs     = (int*)  (ws + 0x10100);
    int*   nmt      = (int*)  (ws + 0x10180);
    int*   te       = (int*)  (ws + 0x10200);
    int*   tr0      = (int*)  (ws + 0x10400);
    int*   trn      = (int*)  (ws + 0x10600);
    int*   pair_tok = (int*)  (ws + 0x10800);
    float* pair_w   = (float*)(ws + 0x18800);
    unsigned short* gated = (unsigned short*)(ws + 0x21000);  // 8192*768 bf16 = 12.6MB

    hipMemsetAsync(d_out, 0, (size_t)out_size*sizeof(float), stream);
    hipMemsetAsync(counts, 0, NEXPERT*sizeof(int), stream);

    router_k <<<T_TOKENS, 64, 0, stream>>>(x, gate, topk_id, topk_w, counts);
    sched_k  <<<1, 64, 0, stream>>>(counts, offs, cursors, nmt, te, tr0, trn);
    scatter_k<<<NPAIRS/256, 256, 0, stream>>>(topk_id, topk_w, cursors, pair_tok, pair_w);
    gemm1_k  <<<MT_MAX*NT1, 256, 0, stream>>>(x, gup, nmt, te, tr0, trn, pair_tok, pair_w, gated);
    gemm2_k  <<<MT_MAX*NT2, 256, 0, stream>>>(gated, down, nmt, te, tr0, trn, pair_tok, out);
}

// Round 2
// 429.048 us; speedup vs baseline: 1.1865x; 1.1865x over previous
//
#include <hip/hip_runtime.h>

#define T_TOKENS 2048
#define HIDDEN   2048
#define NEXPERT  32
#define TOPK     4
#define INTER    768
#define NPAIRS   (T_TOKENS*TOPK)   /* 8192 */
#define BM       128
#define BK       32
#define MT_MAX   95                /* sum ceil(cnt/128) <= 64 + 31 */
#define NT1      12                /* 768/64 gated col-tiles */
#define NT2      16                /* 2048/128 out col-tiles */
#define NK1      (HIDDEN/BK)       /* 64 */
#define NK2      (INTER/BK)        /* 24 */

typedef short  bh8 __attribute__((ext_vector_type(8)));   // 8 bf16
typedef float  fx4 __attribute__((ext_vector_type(4)));

#define AS1 __attribute__((address_space(1)))
#define AS3 __attribute__((address_space(3)))

// async global->LDS, 16B per lane; LDS dest = wave-uniform base + lane*16
__device__ __forceinline__ void gload_lds16(const void* g, const void* lds_generic){
    __builtin_amdgcn_global_load_lds(
        (const AS1 void*)(unsigned long long)g,
        (AS3 void*)(unsigned int)(unsigned long long)lds_generic,
        16, 0, 0);
}

// pack two f32 -> two bf16 (round-half-up: 2 adds + 1 v_perm)
__device__ __forceinline__ unsigned int pack2bf(float a, float b){
    unsigned ua = __float_as_uint(a) + 0x8000u;
    unsigned ub = __float_as_uint(b) + 0x8000u;
    return __builtin_amdgcn_perm(ub, ua, 0x07060302u); // [ub.hi16 : ua.hi16]
}
__device__ __forceinline__ unsigned short f2bfu(float f){
    return (unsigned short)((__float_as_uint(f) + 0x8000u) >> 16);
}

/* ---------------- x -> bf16 ---------------- */
__global__ void cvt_x_k(const float* __restrict__ x, unsigned short* __restrict__ xb){
    int i = (blockIdx.x*256 + threadIdx.x)*8;
    float4 a = *(const float4*)(x+i);
    float4 b = *(const float4*)(x+i+4);
    uint4 o;
    o.x = pack2bf(a.x,a.y); o.y = pack2bf(a.z,a.w);
    o.z = pack2bf(b.x,b.y); o.w = pack2bf(b.z,b.w);
    *(uint4*)(xb+i) = o;
}

/* ---------------- router ---------------- */
__global__ void router_k(const float* __restrict__ x, const float* __restrict__ gate,
                         int* __restrict__ topk_id, float* __restrict__ topk_w,
                         int* __restrict__ counts){
    const int t = blockIdx.x;
    const int l = threadIdx.x;
    const float* xr = x + (size_t)t*HIDDEN;
    float acc[NEXPERT];
#pragma unroll
    for (int e=0;e<NEXPERT;e++) acc[e]=0.f;
    for (int d=l; d<HIDDEN; d+=64){
        float xv = xr[d];
        const float4* g4 = (const float4*)(gate + (size_t)d*NEXPERT);
#pragma unroll
        for (int i=0;i<8;i++){
            float4 g = g4[i];
            acc[i*4+0] += xv*g.x; acc[i*4+1] += xv*g.y;
            acc[i*4+2] += xv*g.z; acc[i*4+3] += xv*g.w;
        }
    }
#pragma unroll
    for (int e=0;e<NEXPERT;e++){
#pragma unroll
        for (int m=1;m<64;m<<=1) acc[e] += __shfl_xor(acc[e], m, 64);
    }
    int ids[TOPK]; float lv[TOPK];
#pragma unroll
    for (int k=0;k<TOPK;k++){
        float m=-1e30f; int mi=0;
#pragma unroll
        for (int e=0;e<NEXPERT;e++){ if (acc[e]>m){ m=acc[e]; mi=e; } }
        ids[k]=mi; lv[k]=m; acc[mi]=-1e30f;
    }
    float ex[TOPK]; float s=0.f;
#pragma unroll
    for (int k=0;k<TOPK;k++){ ex[k]=__expf(lv[k]-lv[0]); s+=ex[k]; }
    if (l==0){
        float inv = 1.f/s;
#pragma unroll
        for (int k=0;k<TOPK;k++){
            topk_id[t*TOPK+k]=ids[k];
            topk_w[t*TOPK+k]=ex[k]*inv;
            atomicAdd(&counts[ids[k]],1);
        }
    }
}

/* ---------------- schedule ---------------- */
__global__ void sched_k(const int* __restrict__ counts, int* __restrict__ offs,
                        int* __restrict__ cursors, int* __restrict__ nmt,
                        int* __restrict__ te, int* __restrict__ tr0, int* __restrict__ trn){
    if (threadIdx.x==0 && blockIdx.x==0){
        int tot=0, nm=0;
        for (int e=0;e<NEXPERT;e++){
            int c = counts[e];
            offs[e]=tot; cursors[e]=tot;
            for (int s=0;s<c;s+=BM){
                te[nm]=e; tr0[nm]=tot+s; trn[nm]=(c-s)<BM?(c-s):BM; nm++;
            }
            tot+=c;
        }
        *nmt = nm;
    }
}

/* ---------------- scatter ---------------- */
__global__ void scatter_k(const int* __restrict__ topk_id, const float* __restrict__ topk_w,
                          int* __restrict__ cursors, int* __restrict__ pair_tok,
                          float* __restrict__ pair_w){
    int g = blockIdx.x*256 + threadIdx.x;
    int e = topk_id[g];
    float w = topk_w[g];
    int pos = atomicAdd(&cursors[e],1);
    pair_tok[pos] = g>>2;
    pair_w[pos]  = w;
}

/* ============== grouped GEMM1: xb(bf16) x gup(f32->bf16) -> gated(bf16) ============== */
__global__ __launch_bounds__(256) void gemm1_k(
        const unsigned short* __restrict__ xb, const float* __restrict__ gup,
        const int* __restrict__ nmt, const int* __restrict__ te,
        const int* __restrict__ tr0, const int* __restrict__ trn,
        const int* __restrict__ pair_tok, const float* __restrict__ pair_w,
        unsigned short* __restrict__ gated){
    __shared__ __align__(16) unsigned short As[2][BM*32]; // linear 64B rows, src-swizzled chunks
    __shared__ __align__(16) unsigned short Bs[BM*40];    // [col][40] pitch 80B, chunk = kc ^ ((col>>3)&3)
    __shared__ int   s_tok[BM];
    __shared__ float s_w[BM];

    const int nwg = gridDim.x;
    const int q = nwg>>3, r = nwg&7;
    const int xcd = blockIdx.x & 7, bidx = blockIdx.x >> 3;
    const int L = (xcd<r ? xcd*(q+1) : r*(q+1)+(xcd-r)*q) + bidx;
    const int mt = L % MT_MAX, nt = L / MT_MAX;
    if (mt >= *nmt) return;
    const int e = te[mt], row0 = tr0[mt], rows = trn[mt];
    const int n0 = nt*64;

    const int t = threadIdx.x;
    if (t < BM){
        int p = row0 + t; if (p > NPAIRS-1) p = NPAIRS-1;
        s_tok[t] = pair_tok[p];
        s_w[t]   = pair_w[p];
    }
    __syncthreads();

    const int w = t>>6, lane = t&63;
    const int l15 = lane & 15, kb = lane >> 4;

    // ---- A DMA (gathered bf16 x rows) ----
    const int arow0 = w*16 + (lane>>2);               // inst0 rows 0..63
    const int arow1 = 64 + arow0;                     // inst1 rows 64..127
    const int ck0 = (lane&3) ^ ((lane>>3)&3);         // src chunk swizzle (= kb ^ s(row))
    const unsigned short* asrc0 = xb + (size_t)s_tok[arow0]*HIDDEN + ck0*8;
    const unsigned short* asrc1 = xb + (size_t)s_tok[arow1]*HIDDEN + ck0*8;
    const unsigned short* adst0[2] = { &As[0][(w*16)*32],      &As[1][(w*16)*32] };
    const unsigned short* adst1[2] = { &As[0][(64+w*16)*32],   &As[1][(64+w*16)*32] };

    // ---- B staging (f32 -> bf16 register 4x4 transpose) ----
    const int j5 = t & 31, col4 = j5*4;
    const int bd0 = (t>>5)*4;
    const int gq = (j5>>1)&3;                         // ((col)>>3)&3, uniform over col4..col4+3
    const unsigned wb = (unsigned)(col4*80 + (((bd0>>3) ^ gq)<<4) + (bd0&4)*2);
    const int fc = (col4 < 64) ? (n0 + col4) : (704 + n0 + col4);
    const float* bsrc = gup + (size_t)e*HIDDEN*(2*INTER) + (size_t)bd0*(2*INTER) + fc;

    fx4 acc[2][8];
#pragma unroll
    for (int i=0;i<2;i++)
#pragma unroll
        for (int j=0;j<8;j++) acc[i][j] = (fx4)0.f;

    // prologue
    gload_lds16(asrc0, adst0[0]);
    gload_lds16(asrc1, adst1[0]);
    float4 rv0 = *(const float4*)(bsrc);
    float4 rv1 = *(const float4*)(bsrc + 2*INTER);
    float4 rv2 = *(const float4*)(bsrc + 4*INTER);
    float4 rv3 = *(const float4*)(bsrc + 6*INTER);

    const int sA = (l15>>1)&3;                        // A read swizzle
    char* bsb = (char*)Bs;
    for (int k=0; k<NK1; ++k){
        __syncthreads();                              // MFMA(k-1) done; regs/DMA(k) drained
        *(uint2*)(bsb + wb      ) = make_uint2(pack2bf(rv0.x,rv1.x), pack2bf(rv2.x,rv3.x));
        *(uint2*)(bsb + wb +  80) = make_uint2(pack2bf(rv0.y,rv1.y), pack2bf(rv2.y,rv3.y));
        *(uint2*)(bsb + wb + 160) = make_uint2(pack2bf(rv0.z,rv1.z), pack2bf(rv2.z,rv3.z));
        *(uint2*)(bsb + wb + 240) = make_uint2(pack2bf(rv0.w,rv1.w), pack2bf(rv2.w,rv3.w));
        __syncthreads();                              // Bs(k) visible
        if (k+1 < NK1){
            const float* b2 = bsrc + (size_t)(k+1)*BK*(2*INTER);
            rv0 = *(const float4*)(b2);
            rv1 = *(const float4*)(b2 + 2*INTER);
            rv2 = *(const float4*)(b2 + 4*INTER);
            rv3 = *(const float4*)(b2 + 6*INTER);
            gload_lds16(asrc0 + (k+1)*BK, adst0[(k+1)&1]);
            gload_lds16(asrc1 + (k+1)*BK, adst1[(k+1)&1]);
        }
        const unsigned short* Ak = As[k&1];
        bh8 a0 = *(const bh8*)(Ak + (w*32+l15)*32    + ((kb ^ sA)<<3));
        bh8 a1 = *(const bh8*)(Ak + (w*32+16+l15)*32 + ((kb ^ sA)<<3));
#pragma unroll
        for (int c=0;c<8;c++){
            const int bc = c*16 + l15;
            bh8 b = *(const bh8*)(bsb + bc*80 + ((kb ^ ((bc>>3)&3))<<4));
            acc[0][c] = __builtin_amdgcn_mfma_f32_16x16x32_bf16(a0, b, acc[0][c], 0,0,0);
            acc[1][c] = __builtin_amdgcn_mfma_f32_16x16x32_bf16(a1, b, acc[1][c], 0,0,0);
        }
    }

    // epilogue: gated = silu(g)*u*router_w
    const int rbase = w*32 + kb*4;
#pragma unroll
    for (int mr=0;mr<2;mr++){
#pragma unroll
        for (int qq=0;qq<4;qq++){
            int row = rbase + mr*16 + qq;
            if (row < rows){
                float wgt = s_w[row];
                size_t prow = (size_t)(row0 + row)*INTER + n0 + l15;
#pragma unroll
                for (int c=0;c<4;c++){
                    float g = acc[mr][c][qq], u = acc[mr][c+4][qq];
                    float sil = g / (1.f + __expf(-g));
                    gated[prow + c*16] = f2bfu(sil*u*wgt);
                }
            }
        }
    }
}

/* ============== grouped GEMM2: gated(bf16) x down(f32->bf16) -> out (atomic f32) ============== */
__global__ __launch_bounds__(256) void gemm2_k(
        const unsigned short* __restrict__ gated, const float* __restrict__ down,
        const int* __restrict__ nmt, const int* __restrict__ te,
        const int* __restrict__ tr0, const int* __restrict__ trn,
        const int* __restrict__ pair_tok, float* __restrict__ out){
    __shared__ __align__(16) unsigned short As[2][BM*32];
    __shared__ __align__(16) unsigned short Bs[BM*40];
    __shared__ int s_tok[BM];

    const int nwg = gridDim.x;
    const int q = nwg>>3, r = nwg&7;
    const int xcd = blockIdx.x & 7, bidx = blockIdx.x >> 3;
    const int L = (xcd<r ? xcd*(q+1) : r*(q+1)+(xcd-r)*q) + bidx;
    const int mt = L % MT_MAX, nt = L / MT_MAX;
    if (mt >= *nmt) return;
    const int e = te[mt], row0 = tr0[mt], rows = trn[mt];
    const int n0 = nt*128;

    const int t = threadIdx.x;
    if (t < BM){
        int p = row0 + t; if (p > NPAIRS-1) p = NPAIRS-1;
        s_tok[t] = pair_tok[p];
    }
    __syncthreads();

    const int w = t>>6, lane = t&63;
    const int l15 = lane & 15, kb = lane >> 4;

    const int arow0 = w*16 + (lane>>2);
    const int arow1 = 64 + arow0;
    const int ck0 = (lane&3) ^ ((lane>>3)&3);
    const unsigned short* asrc0 = gated + (size_t)(row0 + arow0)*INTER + ck0*8;
    const unsigned short* asrc1 = gated + (size_t)(row0 + arow1)*INTER + ck0*8;
    const unsigned short* adst0[2] = { &As[0][(w*16)*32],    &As[1][(w*16)*32] };
    const unsigned short* adst1[2] = { &As[0][(64+w*16)*32], &As[1][(64+w*16)*32] };

    const int j5 = t & 31, col4 = j5*4;
    const int bd0 = (t>>5)*4;
    const int gq = (j5>>1)&3;
    const unsigned wb = (unsigned)(col4*80 + (((bd0>>3) ^ gq)<<4) + (bd0&4)*2);
    const float* bsrc = down + (size_t)e*INTER*HIDDEN + (size_t)bd0*HIDDEN + (n0 + col4);

    fx4 acc[2][8];
#pragma unroll
    for (int i=0;i<2;i++)
#pragma unroll
        for (int j=0;j<8;j++) acc[i][j] = (fx4)0.f;

    gload_lds16(asrc0, adst0[0]);
    gload_lds16(asrc1, adst1[0]);
    float4 rv0 = *(const float4*)(bsrc);
    float4 rv1 = *(const float4*)(bsrc + HIDDEN);
    float4 rv2 = *(const float4*)(bsrc + 2*HIDDEN);
    float4 rv3 = *(const float4*)(bsrc + 3*HIDDEN);

    const int sA = (l15>>1)&3;
    char* bsb = (char*)Bs;
    for (int k=0; k<NK2; ++k){
        __syncthreads();
        *(uint2*)(bsb + wb      ) = make_uint2(pack2bf(rv0.x,rv1.x), pack2bf(rv2.x,rv3.x));
        *(uint2*)(bsb + wb +  80) = make_uint2(pack2bf(rv0.y,rv1.y), pack2bf(rv2.y,rv3.y));
        *(uint2*)(bsb + wb + 160) = make_uint2(pack2bf(rv0.z,rv1.z), pack2bf(rv2.z,rv3.z));
        *(uint2*)(bsb + wb + 240) = make_uint2(pack2bf(rv0.w,rv1.w), pack2bf(rv2.w,rv3.w));
        __syncthreads();
        if (k+1 < NK2){
            const float* b2 = bsrc + (size_t)(k+1)*BK*HIDDEN;
            rv0 = *(const float4*)(b2);
            rv1 = *(const float4*)(b2 + HIDDEN);
            rv2 = *(const float4*)(b2 + 2*HIDDEN);
            rv3 = *(const float4*)(b2 + 3*HIDDEN);
            gload_lds16(asrc0 + (k+1)*BK, adst0[(k+1)&1]);
            gload_lds16(asrc1 + (k+1)*BK, adst1[(k+1)&1]);
        }
        const unsigned short* Ak = As[k&1];
        bh8 a0 = *(const bh8*)(Ak + (w*32+l15)*32    + ((kb ^ sA)<<3));
        bh8 a1 = *(const bh8*)(Ak + (w*32+16+l15)*32 + ((kb ^ sA)<<3));
#pragma unroll
        for (int c=0;c<8;c++){
            const int bc = c*16 + l15;
            bh8 b = *(const bh8*)(bsb + bc*80 + ((kb ^ ((bc>>3)&3))<<4));
            acc[0][c] = __builtin_amdgcn_mfma_f32_16x16x32_bf16(a0, b, acc[0][c], 0,0,0);
            acc[1][c] = __builtin_amdgcn_mfma_f32_16x16x32_bf16(a1, b, acc[1][c], 0,0,0);
        }
    }

    const int rbase = w*32 + kb*4;
#pragma unroll
    for (int mr=0;mr<2;mr++){
#pragma unroll
        for (int qq=0;qq<4;qq++){
            int row = rbase + mr*16 + qq;
            if (row < rows){
                float* orow = out + (size_t)s_tok[row]*HIDDEN + n0 + l15;
#pragma unroll
                for (int c=0;c<8;c++)
                    atomicAdd(orow + c*16, acc[mr][c][qq]);
            }
        }
    }
}

/* ---------------- host launch ---------------- */
extern "C" void kernel_launch(void* const* d_in, const int* in_sizes, int n_in,
                              void* d_out, int out_size, void* d_ws, size_t ws_size,
                              hipStream_t stream){
    const float* x    = (const float*)d_in[0];
    const float* gate = (const float*)d_in[1];
    const float* gup  = (const float*)d_in[2];
    const float* down = (const float*)d_in[3];
    float* out = (float*)d_out;
    char*  ws  = (char*)d_ws;

    int*   topk_id  = (int*)  (ws + 0x00000);
    float* topk_w   = (float*)(ws + 0x08000);
    int*   counts   = (int*)  (ws + 0x10000);
    int*   cursors  = (int*)  (ws + 0x10080);
    int*   offs     = (int*)  (ws + 0x10100);
    int*   nmt      = (int*)  (ws + 0x10180);
    int*   te       = (int*)  (ws + 0x10200);
    int*   tr0      = (int*)  (ws + 0x10400);
    int*   trn      = (int*)  (ws + 0x10600);
    int*   pair_tok = (int*)  (ws + 0x10800);
    float* pair_w   = (float*)(ws + 0x18800);
    unsigned short* gated = (unsigned short*)(ws + 0x21000);    // 8320*768*2 = 12.78MB (incl. overrun pad)
    unsigned short* xb    = (unsigned short*)(ws + 0xC60000);   // 2048*2048*2 = 8MB

    hipMemsetAsync(d_out, 0, (size_t)out_size*sizeof(float), stream);
    hipMemsetAsync(counts, 0, NEXPERT*sizeof(int), stream);

    cvt_x_k  <<<T_TOKENS*HIDDEN/(256*8), 256, 0, stream>>>(x, xb);
    router_k <<<T_TOKENS, 64, 0, stream>>>(x, gate, topk_id, topk_w, counts);
    sched_k  <<<1, 64, 0, stream>>>(counts, offs, cursors, nmt, te, tr0, trn);
    scatter_k<<<NPAIRS/256, 256, 0, stream>>>(topk_id, topk_w, cursors, pair_tok, pair_w);
    gemm1_k  <<<MT_MAX*NT1, 256, 0, stream>>>(xb, gup, nmt, te, tr0, trn, pair_tok, pair_w, gated);
    gemm2_k  <<<MT_MAX*NT2, 256, 0, stream>>>(gated, down, nmt, te, tr0, trn, pair_tok, out);
}